// Round 14
// baseline (269.901 us; speedup 1.0000x reference)
//
#include <hip/hip_runtime.h>

#define IMGS 64
#define HH 512
#define WW 512
#define NPIX (HH * WW)          // 262144 pixels per image
#define STEPS 10
#define RSTRIP 16               // rows per wave strip in A-pass kconv
#define NBLK (IMGS * 32)        // A-pass: 2048 blocks x 128 thr (16-row tiles)
#define FROWS 8                 // kfuse output rows per block
#define NBLKF (IMGS * 64)       // kfuse: 4096 blocks x 128 thr (8-row tiles)
#define WPI 64                  // stat partials per image per step

// ---------------------------------------------------------------------------
// kconv<FIRST,STORE>: one erosion step, register sliding-window stencil.
// Used ONLY as stats-passes here (STORE=0): A0 reads x,y; A2..A8 read f_{k-1}
// normalized on the fly. Writes per-wave min/max(f32)+sum(f64) partials.
// ---------------------------------------------------------------------------
template <int FIRST, int STORE>
__global__ __launch_bounds__(128) void kconv(const float* __restrict__ xg,
                                             const float* __restrict__ yg,
                                             const float* __restrict__ src,
                                             float* __restrict__ dst,
                                             const float2* __restrict__ prevMM,
                                             float2* __restrict__ pmm,
                                             double* __restrict__ psum) {
    const int bid = blockIdx.x;
    const int swz = (bid & 7) * (NBLK / 8) + (bid >> 3);  // XCD-contiguous
    const int img = swz >> 5;
    const int blk = swz & 31;
    const int tid = threadIdx.x;
    const int w = tid >> 6;
    const int lane = tid & 63;
    const int vc = w * 64 + lane;
    const int ys = blk * RSTRIP;
    const size_t base = (size_t)img * NPIX;

    float scale = 1.0f, off = 0.0f;
    if (!FIRST) {
        float2 a = prevMM[img * WPI + lane];
        float tmn = a.x, tmx = a.y;
        #pragma unroll
        for (int o2 = 32; o2 > 0; o2 >>= 1) {
            tmn = fminf(tmn, __shfl_xor(tmn, o2));
            tmx = fmaxf(tmx, __shfl_xor(tmx, o2));
        }
        float ptp = tmx - tmn;
        if (ptp > 0.0f) { scale = 1.0f / ptp; off = tmn * scale; }
    }

    const float4* xv = (const float4*)(xg + base);
    const float4* yv = (const float4*)(yg + base);
    const float4* sv = (const float4*)(src + base);

    auto ld4 = [&](int r) -> float4 {
        if (FIRST) {
            float4 a = xv[r * 128 + vc];
            float4 b = yv[r * 128 + vc];
            float4 v;
            v.x = (a.x - b.x) * (a.x - b.x);
            v.y = (a.y - b.y) * (a.y - b.y);
            v.z = (a.z - b.z) * (a.z - b.z);
            v.w = (a.w - b.w) * (a.w - b.w);
            return v;
        } else {
            float4 v = sv[r * 128 + vc];
            v.x = fmaf(v.x, scale, -off);
            v.y = fmaf(v.y, scale, -off);
            v.z = fmaf(v.z, scale, -off);
            v.w = fmaf(v.w, scale, -off);
            return v;
        }
    };
    auto ld1 = [&](int r, int pcol) -> float {
        if (FIRST) {
            float d = xg[base + r * WW + pcol] - yg[base + r * WW + pcol];
            return d * d;
        } else {
            return fmaf(src[base + r * WW + pcol], scale, -off);
        }
    };

    const float4 z4 = make_float4(0.f, 0.f, 0.f, 0.f);
    float4 pm1 = (ys > 0) ? ld4(ys - 1) : z4;
    float4 p0 = ld4(ys);

    float tmin = __uint_as_float(0x7f800000u);
    float tmax = 0.0f;
    float tsum = 0.0f;
    float4* dv = (float4*)(dst + base);

    #pragma unroll
    for (int i = 0; i < RSTRIP; ++i) {
        const int y = ys + i;
        float4 p1 = (y + 1 < HH) ? ld4(y + 1) : z4;

        float lf = __shfl_up(p0.w, 1);
        float rt = __shfl_down(p0.x, 1);
        if (lane == 0)  lf = (vc > 0)   ? ld1(y, vc * 4 - 1) : 0.0f;
        if (lane == 63) rt = (vc < 127) ? ld1(y, vc * 4 + 4) : 0.0f;

        float4 e;
        e.x = 0.2f * (pm1.x + p1.x + lf   + p0.x + p0.y);
        e.y = 0.2f * (pm1.y + p1.y + p0.x + p0.y + p0.z);
        e.z = 0.2f * (pm1.z + p1.z + p0.y + p0.z + p0.w);
        e.w = 0.2f * (pm1.w + p1.w + p0.z + p0.w + rt);
        e.x = fmaxf(e.x - 0.5f, 0.0f);
        e.y = fmaxf(e.y - 0.5f, 0.0f);
        e.z = fmaxf(e.z - 0.5f, 0.0f);
        e.w = fmaxf(e.w - 0.5f, 0.0f);

        if (STORE) dv[y * 128 + vc] = e;

        tmin = fminf(tmin, fminf(fminf(e.x, e.y), fminf(e.z, e.w)));
        tmax = fmaxf(tmax, fmaxf(fmaxf(e.x, e.y), fmaxf(e.z, e.w)));
        tsum += (e.x + e.y) + (e.z + e.w);

        pm1 = p0;
        p0 = p1;
    }

    double dsum = (double)tsum;
    #pragma unroll
    for (int o2 = 32; o2 > 0; o2 >>= 1) {
        tmin = fminf(tmin, __shfl_down(tmin, o2));
        tmax = fmaxf(tmax, __shfl_down(tmax, o2));
        dsum += __shfl_down(dsum, o2);
    }

    if (lane == 0) {
        const int idx = img * WPI + blk * 2 + w;
        pmm[idx] = make_float2(tmin, tmax);
        psum[idx] = dsum;
    }
}

// ---------------------------------------------------------------------------
// kfuse<FIRST,STORE>: TWO erosion steps, LDS phase-split.
//   Phase 1 (identical arithmetic to kconv): compute ero_k rows ys-1..ys+8
//   (normalized by this pair's mmB stats) into LDS[10][512]; rows/cols OOB
//   of the image are exact zeros.  Phase 2: second 5-tap stencil straight
//   from LDS (no shuffles, no divergent loads; cross-wave edges via LDS),
//   -> ero_{k+1}; STORE? write f_{k+1}; block-reduced stats either way.
//   FIRST: phase-1 source is (x-y)^2 on the fly (mmA unused).
// ---------------------------------------------------------------------------
template <int FIRST, int STORE>
__global__ __launch_bounds__(128) void kfuse(const float* __restrict__ xg,
                                             const float* __restrict__ yg,
                                             const float* __restrict__ src,
                                             float* __restrict__ dst,
                                             const float2* __restrict__ mmA,
                                             const float2* __restrict__ mmB,
                                             float2* __restrict__ pmm,
                                             double* __restrict__ psum) {
    const int bid = blockIdx.x;
    const int swz = (bid & 7) * (NBLKF / 8) + (bid >> 3);
    const int img = swz >> 6;             // 64 blocks per image
    const int blk = swz & 63;
    const int tid = threadIdx.x;
    const int w = tid >> 6;
    const int lane = tid & 63;
    const int vc = w * 64 + lane;         // vec4 column [0,128)
    const int ys = blk * FROWS;
    const size_t base = (size_t)img * NPIX;

    __shared__ float lds[10][512];        // 20 KB

    // stats butterflies: s1 (input norm, unless FIRST) and s2 (ero_k norm)
    float s1 = 1.0f, o1 = 0.0f;
    if (!FIRST) {
        float2 a = mmA[img * WPI + lane];
        float mn = a.x, mx = a.y;
        #pragma unroll
        for (int o2 = 32; o2 > 0; o2 >>= 1) {
            mn = fminf(mn, __shfl_xor(mn, o2));
            mx = fmaxf(mx, __shfl_xor(mx, o2));
        }
        float p = mx - mn;
        if (p > 0.0f) { s1 = 1.0f / p; o1 = mn * s1; }
    }
    float s2 = 1.0f, o2v = 0.0f;
    {
        float2 a = mmB[img * WPI + lane];
        float mn = a.x, mx = a.y;
        #pragma unroll
        for (int o2 = 32; o2 > 0; o2 >>= 1) {
            mn = fminf(mn, __shfl_xor(mn, o2));
            mx = fmaxf(mx, __shfl_xor(mx, o2));
        }
        float p = mx - mn;
        if (p > 0.0f) { s2 = 1.0f / p; o2v = mn * s2; }
    }

    const float4* xv = (const float4*)(xg + base);
    const float4* yv = (const float4*)(yg + base);
    const float4* sv = (const float4*)(src + base);

    auto ld4 = [&](int r) -> float4 {     // source row r (guaranteed in-bounds)
        if (FIRST) {
            float4 a = xv[r * 128 + vc];
            float4 b = yv[r * 128 + vc];
            float4 v;
            v.x = (a.x - b.x) * (a.x - b.x);
            v.y = (a.y - b.y) * (a.y - b.y);
            v.z = (a.z - b.z) * (a.z - b.z);
            v.w = (a.w - b.w) * (a.w - b.w);
            return v;
        } else {
            float4 v = sv[r * 128 + vc];
            v.x = fmaf(v.x, s1, -o1);
            v.y = fmaf(v.y, s1, -o1);
            v.z = fmaf(v.z, s1, -o1);
            v.w = fmaf(v.w, s1, -o1);
            return v;
        }
    };
    auto ld1 = [&](int r, int pcol) -> float {
        if (FIRST) {
            float d = xg[base + r * WW + pcol] - yg[base + r * WW + pcol];
            return d * d;
        } else {
            return fmaf(src[base + r * WW + pcol], s1, -o1);
        }
    };

    const float4 z4 = make_float4(0.f, 0.f, 0.f, 0.f);

    // phase 1: ero_k rows r = ys-1 .. ys+8 -> lds[j], normalized by s2
    float4 fm1 = (ys >= 2) ? ld4(ys - 2) : z4;
    float4 f0  = (ys >= 1) ? ld4(ys - 1) : z4;
    #pragma unroll
    for (int j = 0; j < FROWS + 2; ++j) {
        const int r = ys - 1 + j;
        float4 f1 = (r + 1 < HH) ? ld4(r + 1) : z4;   // r+1 >= 0 always
        float4 e = z4;
        if (r >= 0 && r < HH) {
            float lf = __shfl_up(f0.w, 1);
            float rt = __shfl_down(f0.x, 1);
            if (lane == 0)  lf = (vc > 0)   ? ld1(r, vc * 4 - 1) : 0.0f;
            if (lane == 63) rt = (vc < 127) ? ld1(r, vc * 4 + 4) : 0.0f;
            float4 t;
            t.x = 0.2f * (fm1.x + f1.x + lf   + f0.x + f0.y);
            t.y = 0.2f * (fm1.y + f1.y + f0.x + f0.y + f0.z);
            t.z = 0.2f * (fm1.z + f1.z + f0.y + f0.z + f0.w);
            t.w = 0.2f * (fm1.w + f1.w + f0.z + f0.w + rt);
            t.x = fmaxf(t.x - 0.5f, 0.0f);
            t.y = fmaxf(t.y - 0.5f, 0.0f);
            t.z = fmaxf(t.z - 0.5f, 0.0f);
            t.w = fmaxf(t.w - 0.5f, 0.0f);
            e.x = fmaf(t.x, s2, -o2v);
            e.y = fmaf(t.y, s2, -o2v);
            e.z = fmaf(t.z, s2, -o2v);
            e.w = fmaf(t.w, s2, -o2v);
        }
        *(float4*)&lds[j][4 * vc] = e;
        fm1 = f0;
        f0 = f1;
    }
    __syncthreads();

    // phase 2: second stencil from LDS -> ero_{k+1}
    float tmin = __uint_as_float(0x7f800000u);
    float tmax = 0.0f;
    float tsum = 0.0f;
    float4* dv = (float4*)(dst + base);

    #pragma unroll
    for (int i = 0; i < FROWS; ++i) {
        const int y = ys + i;
        float4 up = *(const float4*)&lds[i][4 * vc];
        float4 c4 = *(const float4*)&lds[i + 1][4 * vc];
        float4 dn = *(const float4*)&lds[i + 2][4 * vc];
        float lf = (vc > 0)   ? lds[i + 1][4 * vc - 1] : 0.0f;
        float rt = (vc < 127) ? lds[i + 1][4 * vc + 4] : 0.0f;

        float4 g;
        g.x = 0.2f * (up.x + dn.x + lf   + c4.x + c4.y);
        g.y = 0.2f * (up.y + dn.y + c4.x + c4.y + c4.z);
        g.z = 0.2f * (up.z + dn.z + c4.y + c4.z + c4.w);
        g.w = 0.2f * (up.w + dn.w + c4.z + c4.w + rt);
        g.x = fmaxf(g.x - 0.5f, 0.0f);
        g.y = fmaxf(g.y - 0.5f, 0.0f);
        g.z = fmaxf(g.z - 0.5f, 0.0f);
        g.w = fmaxf(g.w - 0.5f, 0.0f);

        if (STORE) dv[y * 128 + vc] = g;

        tmin = fminf(tmin, fminf(fminf(g.x, g.y), fminf(g.z, g.w)));
        tmax = fmaxf(tmax, fmaxf(fmaxf(g.x, g.y), fmaxf(g.z, g.w)));
        tsum += (g.x + g.y) + (g.z + g.w);
    }

    double dsum = (double)tsum;
    #pragma unroll
    for (int o2 = 32; o2 > 0; o2 >>= 1) {
        tmin = fminf(tmin, __shfl_down(tmin, o2));
        tmax = fmaxf(tmax, __shfl_down(tmax, o2));
        dsum += __shfl_down(dsum, o2);
    }

    // block-reduce the 2 wave partials via LDS reuse -> 1 partial per block
    __syncthreads();
    if (lane == 0) {
        lds[0][w] = tmin;
        lds[0][2 + w] = tmax;
        ((double*)&lds[2][0])[w] = dsum;
    }
    __syncthreads();
    if (tid == 0) {
        const int idx = img * WPI + blk;
        pmm[idx] = make_float2(fminf(lds[0][0], lds[0][1]),
                               fmaxf(lds[0][2], lds[0][3]));
        psum[idx] = ((double*)&lds[2][0])[0] + ((double*)&lds[2][0])[1];
    }
}

// ---------------------------------------------------------------------------
// kfin1 / kfin2: unchanged.
// ---------------------------------------------------------------------------
__global__ __launch_bounds__(64) void kfin1(const float2* __restrict__ pmm,
                                            const double* __restrict__ psum,
                                            double* __restrict__ perImg) {
    const int img = blockIdx.x;
    const int lane = threadIdx.x;
    double tot = 0.0;
    for (int k = 0; k < STEPS; ++k) {
        const int o = (k * IMGS + img) * WPI;
        float2 a = pmm[o + lane];
        double s = psum[o + lane];
        float tmn = a.x;
        float tmx = a.y;
        #pragma unroll
        for (int o2 = 32; o2 > 0; o2 >>= 1) {
            tmn = fminf(tmn, __shfl_xor(tmn, o2));
            tmx = fmaxf(tmx, __shfl_xor(tmx, o2));
            s += __shfl_xor(s, o2);
        }
        float ptp = tmx - tmn;
        double sn = (ptp > 0.0f)
                        ? (s - (double)NPIX * (double)tmn) / (double)ptp
                        : s;
        tot += sn * (double)((k + 1) * (k + 1));
    }
    if (lane == 0) perImg[img] = tot;
}

__global__ void kfin2(const double* __restrict__ perImg,
                      float* __restrict__ out) {
    double v = perImg[threadIdx.x];
    #pragma unroll
    for (int o2 = 32; o2 > 0; o2 >>= 1) v += __shfl_down(v, o2);
    if (threadIdx.x == 0)
        out[0] = (float)(v / ((double)IMGS * (double)NPIX));
}

// ---------------------------------------------------------------------------
extern "C" void kernel_launch(void* const* d_in, const int* in_sizes, int n_in,
                              void* d_out, int out_size, void* d_ws, size_t ws_size,
                              hipStream_t stream) {
    const float* x = (const float*)d_in[0];
    const float* y = (const float*)d_in[1];
    float* out = (float*)d_out;

    char* ws = (char*)d_ws;
    const size_t bufBytes = (size_t)IMGS * NPIX * sizeof(float);  // 64 MiB
    float* bufA = (float*)ws;
    float* bufB = (float*)(ws + bufBytes);
    char* p = ws + 2 * bufBytes;
    float2* pmm = (float2*)p;        p += (size_t)STEPS * IMGS * WPI * sizeof(float2);
    double* psum = (double*)p;       p += (size_t)STEPS * IMGS * WPI * sizeof(double);
    double* perImg = (double*)p;

    const size_t SLOT = (size_t)IMGS * WPI;

    // pair (0,1): A0 reads x,y -> s0; F0 re-reads x,y (L3-hot) -> f1 + s1
    kconv<1, 0><<<NBLK, 128, 0, stream>>>(x, y, nullptr, nullptr, nullptr,
                                          pmm, psum);
    kfuse<1, 1><<<NBLKF, 128, 0, stream>>>(x, y, nullptr, bufA,
                                           nullptr, pmm,
                                           pmm + SLOT, psum + SLOT);
    float* cur = bufA;   // holds f1
    float* nxt = bufB;
    // pairs (2,3), (4,5), (6,7): A -> s_{2p}; F -> f_{2p+1} + s_{2p+1}
    for (int pr = 1; pr <= 3; ++pr) {
        const int k = 2 * pr;
        kconv<0, 0><<<NBLK, 128, 0, stream>>>(
            nullptr, nullptr, cur, nullptr,
            pmm + (size_t)(k - 1) * SLOT,
            pmm + (size_t)k * SLOT,
            psum + (size_t)k * SLOT);
        kfuse<0, 1><<<NBLKF, 128, 0, stream>>>(
            nullptr, nullptr, cur, nxt,
            pmm + (size_t)(k - 1) * SLOT,
            pmm + (size_t)k * SLOT,
            pmm + (size_t)(k + 1) * SLOT,
            psum + (size_t)(k + 1) * SLOT);
        float* tmp = cur; cur = nxt; nxt = tmp;
    }
    // pair (8,9): A8 -> s8; F8 stats-only (no f9 write)
    kconv<0, 0><<<NBLK, 128, 0, stream>>>(
        nullptr, nullptr, cur, nullptr,
        pmm + (size_t)7 * SLOT,
        pmm + (size_t)8 * SLOT,
        psum + (size_t)8 * SLOT);
    kfuse<0, 0><<<NBLKF, 128, 0, stream>>>(
        nullptr, nullptr, cur, nullptr,
        pmm + (size_t)7 * SLOT,
        pmm + (size_t)8 * SLOT,
        pmm + (size_t)9 * SLOT,
        psum + (size_t)9 * SLOT);

    kfin1<<<IMGS, 64, 0, stream>>>(pmm, psum, perImg);
    kfin2<<<1, 64, 0, stream>>>(perImg, out);
}

// Round 15
// 219.508 us; speedup vs baseline: 1.2296x; 1.2296x over previous
//
#include <hip/hip_runtime.h>

#define IMGS 64
#define HH 512
#define WW 512
#define NPIX (HH * WW)          // 262144 pixels per image
#define STEPS 10
#define RSTRIP 16               // rows per wave strip (halo 18/16 = 1.125x)
#define BLKS_PER_IMG 32         // 512 / 16
#define NBLK (IMGS * BLKS_PER_IMG)   // 2048 blocks, 128 threads each
#define WPI 64                  // partials per image per step (32 blk * 2 waves)

// ---------------------------------------------------------------------------
// kconv<FIRST,STORE>: one erosion step, register sliding-window stencil.
//   Block = 128 threads = 2 waves; wave h owns half-row cols [h*256,h*256+256)
//   x 16 rows, sliding pm1/p0/p1 through registers (each row fetched once per
//   strip; halo = 2 rows per 16).
//   Prev-step stats FUSED at block start: one 64-lane butterfly over the 64
//   float2 partials of step k-1 (512 B broadcast, L2-hit) -> scale/off.
//   FIRST: source = (x-y)^2 on the fly; else prev ero normalized on the fly
//   (per-image affine; OOB taps exact 0 = zero-pad of the normalized field).
//   dil = 0.2*(C+N+S+E+W); ero = max(dil-0.5,0). STORE=0 on the last step
//   skips the 64 MB field write. Per-wave min/max(f32)+sum(f64) partials,
//   plain stores; no LDS, no barriers, no atomics.
//   XCD swizzle: contiguous work chunks per XCD for halo L2 locality.
// ---------------------------------------------------------------------------
template <int FIRST, int STORE>
__global__ __launch_bounds__(128) void kconv(const float* __restrict__ xg,
                                             const float* __restrict__ yg,
                                             const float* __restrict__ src,
                                             float* __restrict__ dst,
                                             const float2* __restrict__ prevMM,
                                             float2* __restrict__ pmm,
                                             double* __restrict__ psum) {
    const int bid = blockIdx.x;
    const int swz = (bid & 7) * (NBLK / 8) + (bid >> 3);  // XCD-contiguous
    const int img = swz >> 5;             // 32 blocks per image
    const int blk = swz & 31;
    const int tid = threadIdx.x;
    const int w = tid >> 6;               // wave = half-row select
    const int lane = tid & 63;
    const int vc = w * 64 + lane;         // vec4 column [0,128)
    const int ys = blk * RSTRIP;
    const size_t base = (size_t)img * NPIX;

    float scale = 1.0f, off = 0.0f;
    if (!FIRST) {
        float2 a = prevMM[img * WPI + lane];
        float tmn = a.x, tmx = a.y;
        #pragma unroll
        for (int o2 = 32; o2 > 0; o2 >>= 1) {
            tmn = fminf(tmn, __shfl_xor(tmn, o2));
            tmx = fmaxf(tmx, __shfl_xor(tmx, o2));
        }
        float ptp = tmx - tmn;
        if (ptp > 0.0f) { scale = 1.0f / ptp; off = tmn * scale; }
    }

    const float4* xv = (const float4*)(xg + base);
    const float4* yv = (const float4*)(yg + base);
    const float4* sv = (const float4*)(src + base);

    auto ld4 = [&](int r) -> float4 {     // row r, this thread's vec4 column
        if (FIRST) {
            float4 a = xv[r * 128 + vc];
            float4 b = yv[r * 128 + vc];
            float4 v;
            v.x = (a.x - b.x) * (a.x - b.x);
            v.y = (a.y - b.y) * (a.y - b.y);
            v.z = (a.z - b.z) * (a.z - b.z);
            v.w = (a.w - b.w) * (a.w - b.w);
            return v;
        } else {
            float4 v = sv[r * 128 + vc];
            v.x = fmaf(v.x, scale, -off);
            v.y = fmaf(v.y, scale, -off);
            v.z = fmaf(v.z, scale, -off);
            v.w = fmaf(v.w, scale, -off);
            return v;
        }
    };
    auto ld1 = [&](int r, int pcol) -> float {
        if (FIRST) {
            float d = xg[base + r * WW + pcol] - yg[base + r * WW + pcol];
            return d * d;
        } else {
            return fmaf(src[base + r * WW + pcol], scale, -off);
        }
    };

    const float4 z4 = make_float4(0.f, 0.f, 0.f, 0.f);
    float4 pm1 = (ys > 0) ? ld4(ys - 1) : z4;
    float4 p0 = ld4(ys);

    float tmin = __uint_as_float(0x7f800000u);
    float tmax = 0.0f;
    float tsum = 0.0f;
    float4* dv = (float4*)(dst + base);

    #pragma unroll
    for (int i = 0; i < RSTRIP; ++i) {
        const int y = ys + i;
        float4 p1 = (y + 1 < HH) ? ld4(y + 1) : z4;

        float lf = __shfl_up(p0.w, 1);
        float rt = __shfl_down(p0.x, 1);
        if (lane == 0)  lf = (vc > 0)   ? ld1(y, vc * 4 - 1) : 0.0f;
        if (lane == 63) rt = (vc < 127) ? ld1(y, vc * 4 + 4) : 0.0f;

        float4 e;
        e.x = 0.2f * (pm1.x + p1.x + lf   + p0.x + p0.y);
        e.y = 0.2f * (pm1.y + p1.y + p0.x + p0.y + p0.z);
        e.z = 0.2f * (pm1.z + p1.z + p0.y + p0.z + p0.w);
        e.w = 0.2f * (pm1.w + p1.w + p0.z + p0.w + rt);
        e.x = fmaxf(e.x - 0.5f, 0.0f);
        e.y = fmaxf(e.y - 0.5f, 0.0f);
        e.z = fmaxf(e.z - 0.5f, 0.0f);
        e.w = fmaxf(e.w - 0.5f, 0.0f);

        if (STORE) dv[y * 128 + vc] = e;

        tmin = fminf(tmin, fminf(fminf(e.x, e.y), fminf(e.z, e.w)));
        tmax = fmaxf(tmax, fmaxf(fmaxf(e.x, e.y), fmaxf(e.z, e.w)));
        tsum += (e.x + e.y) + (e.z + e.w);

        pm1 = p0;
        p0 = p1;
    }

    double dsum = (double)tsum;
    #pragma unroll
    for (int o2 = 32; o2 > 0; o2 >>= 1) {
        tmin = fminf(tmin, __shfl_down(tmin, o2));
        tmax = fmaxf(tmax, __shfl_down(tmax, o2));
        dsum += __shfl_down(dsum, o2);
    }

    if (lane == 0) {
        const int idx = img * WPI + blk * 2 + w;
        pmm[idx] = make_float2(tmin, tmax);
        psum[idx] = dsum;
    }
}

// ---------------------------------------------------------------------------
// kfin1: one block (64 threads) per image. For each step k: butterfly-reduce
// the 64 partials (min/max f32, sum f64), apply sum-of-normalized =
// (S - N*mn)/ptp (or S if ptp==0), weight by (k+1)^2. Store per-image f64.
// ---------------------------------------------------------------------------
__global__ __launch_bounds__(64) void kfin1(const float2* __restrict__ pmm,
                                            const double* __restrict__ psum,
                                            double* __restrict__ perImg) {
    const int img = blockIdx.x;
    const int lane = threadIdx.x;
    double tot = 0.0;
    for (int k = 0; k < STEPS; ++k) {
        const int o = (k * IMGS + img) * WPI;
        float2 a = pmm[o + lane];
        double s = psum[o + lane];
        float tmn = a.x;
        float tmx = a.y;
        #pragma unroll
        for (int o2 = 32; o2 > 0; o2 >>= 1) {
            tmn = fminf(tmn, __shfl_xor(tmn, o2));
            tmx = fmaxf(tmx, __shfl_xor(tmx, o2));
            s += __shfl_xor(s, o2);
        }
        float ptp = tmx - tmn;
        double sn = (ptp > 0.0f)
                        ? (s - (double)NPIX * (double)tmn) / (double)ptp
                        : s;
        tot += sn * (double)((k + 1) * (k + 1));
    }
    if (lane == 0) perImg[img] = tot;
}

// ---------------------------------------------------------------------------
// kfin2: sum 64 per-image doubles, divide, write scalar.
// ---------------------------------------------------------------------------
__global__ void kfin2(const double* __restrict__ perImg,
                      float* __restrict__ out) {
    double v = perImg[threadIdx.x];
    #pragma unroll
    for (int o2 = 32; o2 > 0; o2 >>= 1) v += __shfl_down(v, o2);
    if (threadIdx.x == 0)
        out[0] = (float)(v / ((double)IMGS * (double)NPIX));
}

// ---------------------------------------------------------------------------
extern "C" void kernel_launch(void* const* d_in, const int* in_sizes, int n_in,
                              void* d_out, int out_size, void* d_ws, size_t ws_size,
                              hipStream_t stream) {
    const float* x = (const float*)d_in[0];
    const float* y = (const float*)d_in[1];
    float* out = (float*)d_out;

    char* ws = (char*)d_ws;
    const size_t bufBytes = (size_t)IMGS * NPIX * sizeof(float);  // 64 MiB
    float* bufA = (float*)ws;
    float* bufB = (float*)(ws + bufBytes);
    char* p = ws + 2 * bufBytes;
    float2* pmm = (float2*)p;        p += (size_t)STEPS * IMGS * WPI * sizeof(float2);
    double* psum = (double*)p;       p += (size_t)STEPS * IMGS * WPI * sizeof(double);
    double* perImg = (double*)p;

    // step 0: sources x,y directly
    kconv<1, 1><<<NBLK, 128, 0, stream>>>(x, y, nullptr, bufA, nullptr,
                                          pmm, psum);
    float* cur = bufA;
    float* nxt = bufB;
    for (int k = 1; k < STEPS - 1; ++k) {
        kconv<0, 1><<<NBLK, 128, 0, stream>>>(
            nullptr, nullptr, cur, nxt,
            pmm + (size_t)(k - 1) * IMGS * WPI,
            pmm + (size_t)k * IMGS * WPI,
            psum + (size_t)k * IMGS * WPI);
        float* tmp = cur; cur = nxt; nxt = tmp;
    }
    // last step: stats only, no field write
    kconv<0, 0><<<NBLK, 128, 0, stream>>>(
        nullptr, nullptr, cur, nullptr,
        pmm + (size_t)(STEPS - 2) * IMGS * WPI,
        pmm + (size_t)(STEPS - 1) * IMGS * WPI,
        psum + (size_t)(STEPS - 1) * IMGS * WPI);

    kfin1<<<IMGS, 64, 0, stream>>>(pmm, psum, perImg);
    kfin2<<<1, 64, 0, stream>>>(perImg, out);
}